// Round 9
// baseline (219.504 us; speedup 1.0000x reference)
//
#include <hip/hip_runtime.h>

// ROUND 9 = DIAGNOSTIC. Rounds 4-8: five different main-kernel structures all
// ~30-32us vs ~7us model. Harness poison-fills (40us) hide the kernel from
// top-5 counters, so this round makes the hot kernels visible: REP=4 internal
// repeats (atomicMax idempotent => same output; opaque asm offset defeats CSE).
// Two within-probe variants, both computing the FULL problem:
//   chamfer_diag_a: round-7 structure (2 i-tiles/wave, pair prefetch, ~110 VGPR)
//   chamfer_diag_b: lean (1 i-tile/wave, 2-stage acc pipeline, ~84 VGPR)
// Counters wanted: VGPR_Count, OccupancyPercent, MfmaUtil, VALUBusy,
// SQ_LDS_BANK_CONFLICT per variant. dur_us intentionally regresses this round.
// bf16 hi/lo rep (validated rounds 3-8, absmax 0):
//   A(q) = [qh(3), ql(3), qh(3), hq_h, hq_l,  1,  1, 0,0,0]
//   B(t) = [th(3), th(3), tl(3),  -1,  -1, -ht_h, -ht_l, 0,0,0]

#define NPTS    8192
#define BATCH   4
#define NJ      8
#define JCHUNK  1024               // staged chunk: 32 tiles = 32 KB
#define JTILES  (JCHUNK / 32)      // 32
#define NSLOTS  (2 * BATCH * NPTS) // 65536
#define REP     4

typedef __attribute__((ext_vector_type(8))) short short8v;
typedef __attribute__((ext_vector_type(16))) float f32x16;

__device__ __forceinline__ unsigned enc_f32(float f) {
  unsigned u = __float_as_uint(f);
  return (u & 0x80000000u) ? ~u : (u | 0x80000000u);
}
__device__ __forceinline__ float dec_f32(unsigned u) {
  u = (u & 0x80000000u) ? (u ^ 0x80000000u) : ~u;
  return __uint_as_float(u);
}
__device__ __forceinline__ unsigned short f2bf(float x) {   // RNE bf16
  unsigned u = __float_as_uint(x);
  unsigned r = u + 0x7FFFu + ((u >> 16) & 1u);
  return (unsigned short)(r >> 16);
}
__device__ __forceinline__ float bf2f(unsigned short b) {
  return __uint_as_float((unsigned)b << 16);
}

// Per-point layout (16 shorts contiguous per point) — round 5/6/7 layout.
__global__ __launch_bounds__(256) void prep(
    const float* __restrict__ c1, const float* __restrict__ c2,
    unsigned short* __restrict__ a1, unsigned short* __restrict__ a2,
    unsigned short* __restrict__ b1, unsigned short* __restrict__ b2,
    unsigned* __restrict__ rowbuf) {
  int pid = blockIdx.x * 256 + threadIdx.x;
  if (pid >= BATCH * NPTS) return;
  rowbuf[pid] = 0u;                    // below enc of any real float
  rowbuf[pid + BATCH * NPTS] = 0u;
  const unsigned short one = 0x3F80u, negone = 0xBF80u;
  const float* cs[2] = {c1, c2};
  unsigned short* as[2] = {a1, a2};
  unsigned short* bs[2] = {b1, b2};
  #pragma unroll
  for (int c = 0; c < 2; ++c) {
    float x = cs[c][pid * 3 + 0], y = cs[c][pid * 3 + 1], z = cs[c][pid * 3 + 2];
    unsigned short xh = f2bf(x), yh = f2bf(y), zh = f2bf(z);
    unsigned short xl = f2bf(x - bf2f(xh)), yl = f2bf(y - bf2f(yh)),
                   zl = f2bf(z - bf2f(zh));
    float hn = 0.5f * (x * x + y * y + z * z);
    unsigned short hh = f2bf(hn), hl = f2bf(hn - bf2f(hh));
    unsigned short va[16] = {xh, yh, zh, xl, yl, zl, xh, yh, zh,
                             hh, hl, one, one, 0, 0, 0};
    unsigned short nh = hh ^ 0x8000u, nl = hl ^ 0x8000u;
    unsigned short vb[16] = {xh, yh, zh, xh, yh, zh, xl, yl, zl,
                             negone, negone, nh, nl, 0, 0, 0};
    uint4* da = (uint4*)(as[c] + (size_t)pid * 16);
    da[0] = *(const uint4*)&va[0];
    da[1] = *(const uint4*)&va[8];
    uint4* db = (uint4*)(bs[c] + (size_t)pid * 16);
    db[0] = *(const uint4*)&vb[0];
    db[1] = *(const uint4*)&vb[8];
  }
}

__device__ __forceinline__ void butterfly_store(
    f32x16& mrow, int lane, unsigned* rb) {
  #pragma unroll
  for (int r = 0; r < 16; ++r) {
    float v = mrow[r];
    #pragma unroll
    for (int sh = 1; sh <= 16; sh <<= 1) v = fmaxf(v, __shfl_xor(v, sh, 64));
    mrow[r] = v;
  }
  if ((lane & 31) == 0) {
    int h = lane >> 5;
    #pragma unroll
    for (int r = 0; r < 16; ++r) {
      int row = (r & 3) + 8 * (r >> 2) + 4 * h;   // verified 32x32 C/D map
      atomicMax(rb + row, enc_f32(mrow[r]));
    }
  }
}

// Variant A: round-7 structure. grid = 2(dir) x 4(b) x 32(ig) x 8(jc) = 2048
// blocks x 4 waves; wave owns 2 i-tiles; pair prefetch from LDS.
__global__ __launch_bounds__(256, 4) void chamfer_diag_a(
    const unsigned short* __restrict__ a1, const unsigned short* __restrict__ a2,
    const unsigned short* __restrict__ b1, const unsigned short* __restrict__ b2,
    unsigned* __restrict__ rowbuf) {
  __shared__ __align__(16) unsigned short sB[(JCHUNK + 64) * 16];  // 34 KB (pad: prefetch tail)

  int bid = blockIdx.x;
  int jc  = bid & (NJ - 1);
  int ig  = (bid >> 3) & 31;
  int b   = (bid >> 8) & 3;
  int dir = bid >> 10;

  const unsigned short* A = dir ? a2 : a1;
  const unsigned short* B = dir ? b1 : b2;

  int wave = threadIdx.x >> 6;
  int lane = threadIdx.x & 63;
  int p = lane & 31, h = lane >> 5;
  int i0 = ig * 256 + wave * 64;

  {
    const char* gb = (const char*)(B + ((size_t)b * NPTS + (size_t)jc * JCHUNK) * 16)
                     + wave * 8192 + lane * 16;
    char* lb = (char*)sB + wave * 8192;
    #pragma unroll
    for (int k = 0; k < 8; ++k) {
      __builtin_amdgcn_global_load_lds(
          (const __attribute__((address_space(1))) unsigned int*)(gb + k * 1024),
          (__attribute__((address_space(3))) unsigned int*)(lb + k * 1024),
          16, 0, 0);
    }
  }

  const unsigned short* Abase = A + ((size_t)b * NPTS + i0 + p) * 16 + h * 8;
  short8v af0 = *(const short8v*)(const void*)(Abase);
  short8v af1 = *(const short8v*)(const void*)(Abase + 32 * 16);

  f32x16 zero;
  #pragma unroll
  for (int i = 0; i < 16; ++i) zero[i] = 0.0f;

  __syncthreads();

  unsigned* rb = rowbuf + ((size_t)dir * BATCH + b) * NPTS + i0;

  #pragma unroll 1
  for (int rep = 0; rep < REP; ++rep) {
    int off = 0;
    asm volatile("" : "+v"(off));   // opaque: forces real re-execution per rep
    const short8v* sBq = (const short8v*)(const void*)((const char*)sB + off)
                         + (p * 2 + h);
    f32x16 mrow0, mrow1;
    #pragma unroll
    for (int i = 0; i < 16; ++i) { mrow0[i] = -3.4e38f; mrow1[i] = -3.4e38f; }

    short8v u0 = sBq[0], u1 = sBq[64];
    #pragma unroll 1
    for (int jt = 0; jt < JTILES; jt += 2) {
      short8v n0 = sBq[(size_t)(jt + 2) * 64];   // tail reads pad (unused)
      short8v n1 = sBq[(size_t)(jt + 3) * 64];
      {
        f32x16 x0 = __builtin_amdgcn_mfma_f32_32x32x16_bf16(af0, u0, zero, 0, 0, 0);
        f32x16 x1 = __builtin_amdgcn_mfma_f32_32x32x16_bf16(af0, u1, zero, 0, 0, 0);
        #pragma unroll
        for (int r = 0; r < 16; ++r)
          mrow0[r] = fmaxf(fmaxf(x0[r], x1[r]), mrow0[r]);
      }
      {
        f32x16 x0 = __builtin_amdgcn_mfma_f32_32x32x16_bf16(af1, u0, zero, 0, 0, 0);
        f32x16 x1 = __builtin_amdgcn_mfma_f32_32x32x16_bf16(af1, u1, zero, 0, 0, 0);
        #pragma unroll
        for (int r = 0; r < 16; ++r)
          mrow1[r] = fmaxf(fmaxf(x0[r], x1[r]), mrow1[r]);
      }
      u0 = n0; u1 = n1;
    }
    butterfly_store(mrow0, lane, rb);
    butterfly_store(mrow1, lane, rb + 32);
  }
}

// Variant B: lean. grid = 2 x 4 x 64(ig) x 8(jc) = 4096 blocks x 4 waves;
// wave owns ONE i-tile; static 2-stage acc pipeline; minimal registers.
__global__ __launch_bounds__(256, 4) void chamfer_diag_b(
    const unsigned short* __restrict__ a1, const unsigned short* __restrict__ a2,
    const unsigned short* __restrict__ b1, const unsigned short* __restrict__ b2,
    unsigned* __restrict__ rowbuf) {
  __shared__ __align__(16) unsigned short sB[JCHUNK * 16];  // 32 KB

  int bid = blockIdx.x;
  int jc  = bid & (NJ - 1);
  int ig  = (bid >> 3) & 63;
  int b   = (bid >> 9) & 3;
  int dir = bid >> 11;

  const unsigned short* A = dir ? a2 : a1;
  const unsigned short* B = dir ? b1 : b2;

  int wave = threadIdx.x >> 6;
  int lane = threadIdx.x & 63;
  int p = lane & 31, h = lane >> 5;
  int i0 = ig * 128 + wave * 32;

  {
    const char* gb = (const char*)(B + ((size_t)b * NPTS + (size_t)jc * JCHUNK) * 16)
                     + wave * 8192 + lane * 16;
    char* lb = (char*)sB + wave * 8192;
    #pragma unroll
    for (int k = 0; k < 8; ++k) {
      __builtin_amdgcn_global_load_lds(
          (const __attribute__((address_space(1))) unsigned int*)(gb + k * 1024),
          (__attribute__((address_space(3))) unsigned int*)(lb + k * 1024),
          16, 0, 0);
    }
  }

  short8v af = *(const short8v*)(const void*)(
      A + ((size_t)b * NPTS + i0 + p) * 16 + h * 8);

  f32x16 zero;
  #pragma unroll
  for (int i = 0; i < 16; ++i) zero[i] = 0.0f;

  __syncthreads();

  unsigned* rb = rowbuf + ((size_t)dir * BATCH + b) * NPTS + i0;

  #pragma unroll 1
  for (int rep = 0; rep < REP; ++rep) {
    int off = 0;
    asm volatile("" : "+v"(off));
    const short8v* sBq = (const short8v*)(const void*)((const char*)sB + off)
                         + (p * 2 + h);
    f32x16 mrow;
    #pragma unroll
    for (int i = 0; i < 16; ++i) mrow[i] = -3.4e38f;

    short8v ua = sBq[0];
    f32x16 accA = __builtin_amdgcn_mfma_f32_32x32x16_bf16(af, ua, zero, 0, 0, 0);
    #pragma unroll 1
    for (int jt = 1; jt + 1 < JTILES; jt += 2) {
      short8v ub = sBq[(size_t)jt * 64];
      f32x16 accB = __builtin_amdgcn_mfma_f32_32x32x16_bf16(af, ub, zero, 0, 0, 0);
      #pragma unroll
      for (int r = 0; r < 16; ++r) mrow[r] = fmaxf(mrow[r], accA[r]);
      short8v uc = sBq[(size_t)(jt + 1) * 64];
      accA = __builtin_amdgcn_mfma_f32_32x32x16_bf16(af, uc, zero, 0, 0, 0);
      #pragma unroll
      for (int r = 0; r < 16; ++r) mrow[r] = fmaxf(mrow[r], accB[r]);
    }
    {
      short8v ub = sBq[(size_t)(JTILES - 1) * 64];
      f32x16 accB = __builtin_amdgcn_mfma_f32_32x32x16_bf16(af, ub, zero, 0, 0, 0);
      #pragma unroll
      for (int r = 0; r < 16; ++r) mrow[r] = fmaxf(mrow[r], accA[r]);
      #pragma unroll
      for (int r = 0; r < 16; ++r) mrow[r] = fmaxf(mrow[r], accB[r]);
    }
    butterfly_store(mrow, lane, rb);
  }
}

__global__ __launch_bounds__(1024) void loss_final(
    const unsigned* __restrict__ rowbuf, float* __restrict__ out) {
  int tid = threadIdx.x;
  const uint4* rb4 = (const uint4*)rowbuf;   // 16384 uint4
  float s = 0.0f;
  #pragma unroll
  for (int k = 0; k < NSLOTS / 4096; ++k) {  // 16 iters
    uint4 u = rb4[k * 1024 + tid];
    s = fmaf(-2.0f, dec_f32(u.x), s);
    s = fmaf(-2.0f, dec_f32(u.y), s);
    s = fmaf(-2.0f, dec_f32(u.z), s);
    s = fmaf(-2.0f, dec_f32(u.w), s);
  }
  #pragma unroll
  for (int off = 32; off > 0; off >>= 1) s += __shfl_down(s, off, 64);
  __shared__ float wsum[16];
  if ((tid & 63) == 0) wsum[tid >> 6] = s;
  __syncthreads();
  if (tid == 0) {
    float t = 0.0f;
    #pragma unroll
    for (int w2 = 0; w2 < 16; ++w2) t += wsum[w2];
    out[0] = t;
  }
}

extern "C" void kernel_launch(void* const* d_in, const int* in_sizes, int n_in,
                              void* d_out, int out_size, void* d_ws, size_t ws_size,
                              hipStream_t stream) {
  const float* c1 = (const float*)d_in[0];
  const float* c2 = (const float*)d_in[1];
  float* out = (float*)d_out;

  char* ws = (char*)d_ws;
  unsigned* rowbuf = (unsigned*)ws;                          // 65536 u32 = 256 KB
  unsigned short* a1 = (unsigned short*)(ws + (size_t)NSLOTS * 4);
  unsigned short* a2 = a1 + (size_t)BATCH * NPTS * 16;       // 1 MB each
  unsigned short* b1 = a2 + (size_t)BATCH * NPTS * 16;
  unsigned short* b2 = b1 + (size_t)BATCH * NPTS * 16;

  prep<<<(BATCH * NPTS) / 256, 256, 0, stream>>>(c1, c2, a1, a2, b1, b2, rowbuf);
  chamfer_diag_a<<<2 * BATCH * 32 * NJ, 256, 0, stream>>>(a1, a2, b1, b2, rowbuf);
  chamfer_diag_b<<<2 * BATCH * 64 * NJ, 256, 0, stream>>>(a1, a2, b1, b2, rowbuf);
  loss_final<<<1, 1024, 0, stream>>>(rowbuf, out);
}

// Round 10
// 31.365 us; speedup vs baseline: 6.9983x; 6.9983x over previous
//
#include <hip/hip_runtime.h>

// Chamfer via MFMA, round 10: SWAPPED-OPERAND reduction (lane = query).
// Round-9 diagnosis: DS pipe 66% busy — ds_read_b128 + shfl-butterfly
// (ds_swizzle) dominated; butterflies cost as much as all fragment reads.
// Fix: mfma(target_frag, query_frag) -> cols(lanes)=queries, rows(regs)=
// targets; row-max = in-register max3 tree (8 VALU/tile), NO shuffles in
// the loop; one shfl_xor(32)+fmax per i-tile at the end.
// Wave holds 4 query-tiles -> 4 MFMA per ds_read. Tiled rep layout ->
// sequential 16B/lane LDS reads (conflict-free). Grid 1024 = 4 blocks/CU
// resident, barrier-free after staging. NJ=8 query... j-chunks merged via
// atomicMax on order-encoded u32 (8 contenders, deterministic).
// bf16 hi/lo rep (validated rounds 3-9, absmax 0):
//   A_rep(q) = [qh(3), ql(3), qh(3), hq_h, hq_l,  1,  1, 0,0,0]
//   B_rep(t) = [th(3), th(3), tl(3),  -1,  -1, -ht_h, -ht_l, 0,0,0]
// (dot is slot-symmetric: pairing A_rep[k]*B_rep[k] unchanged by swap)

#define NPTS    8192
#define BATCH   4
#define NJ      8
#define JCHUNK  1024               // targets per block chunk: 32 tiles, 32 KB
#define JTILES  (JCHUNK / 32)      // 32
#define NSLOTS  (2 * BATCH * NPTS) // 65536

typedef __attribute__((ext_vector_type(8))) short short8v;
typedef __attribute__((ext_vector_type(16))) float f32x16;

__device__ __forceinline__ unsigned enc_f32(float f) {
  unsigned u = __float_as_uint(f);
  return (u & 0x80000000u) ? ~u : (u | 0x80000000u);
}
__device__ __forceinline__ float dec_f32(unsigned u) {
  u = (u & 0x80000000u) ? (u ^ 0x80000000u) : ~u;
  return __uint_as_float(u);
}
__device__ __forceinline__ unsigned short f2bf(float x) {   // RNE bf16
  unsigned u = __float_as_uint(x);
  unsigned r = u + 0x7FFFu + ((u >> 16) & 1u);
  return (unsigned short)(r >> 16);
}
__device__ __forceinline__ float bf2f(unsigned short b) {
  return __uint_as_float((unsigned)b << 16);
}

// Tiled rep: element offset for point j (batch b), k-half h:
//   b*131072 + (j>>5)*512 + h*256 + (j&31)*8   [shorts]
__global__ __launch_bounds__(256) void prep(
    const float* __restrict__ c1, const float* __restrict__ c2,
    unsigned short* __restrict__ a1, unsigned short* __restrict__ a2,
    unsigned short* __restrict__ b1, unsigned short* __restrict__ b2,
    unsigned* __restrict__ rowbuf) {
  int pid = blockIdx.x * 256 + threadIdx.x;
  if (pid >= BATCH * NPTS) return;
  rowbuf[pid] = 0u;                    // below enc of any real float
  rowbuf[pid + BATCH * NPTS] = 0u;
  const unsigned short one = 0x3F80u, negone = 0xBF80u;
  int b = pid >> 13, j = pid & (NPTS - 1);
  size_t off0 = (size_t)b * 131072 + (size_t)(j >> 5) * 512 + (size_t)(j & 31) * 8;
  const float* cs[2] = {c1, c2};
  unsigned short* as[2] = {a1, a2};
  unsigned short* bs[2] = {b1, b2};
  #pragma unroll
  for (int c = 0; c < 2; ++c) {
    float x = cs[c][pid * 3 + 0], y = cs[c][pid * 3 + 1], z = cs[c][pid * 3 + 2];
    unsigned short xh = f2bf(x), yh = f2bf(y), zh = f2bf(z);
    unsigned short xl = f2bf(x - bf2f(xh)), yl = f2bf(y - bf2f(yh)),
                   zl = f2bf(z - bf2f(zh));
    float hn = 0.5f * (x * x + y * y + z * z);
    unsigned short hh = f2bf(hn), hl = f2bf(hn - bf2f(hh));
    unsigned short va[16] = {xh, yh, zh, xl, yl, zl, xh, yh, zh,
                             hh, hl, one, one, 0, 0, 0};
    unsigned short nh = hh ^ 0x8000u, nl = hl ^ 0x8000u;
    unsigned short vb[16] = {xh, yh, zh, xh, yh, zh, xl, yl, zl,
                             negone, negone, nh, nl, 0, 0, 0};
    *(uint4*)(as[c] + off0)       = *(const uint4*)&va[0];
    *(uint4*)(as[c] + off0 + 256) = *(const uint4*)&va[8];
    *(uint4*)(bs[c] + off0)       = *(const uint4*)&vb[0];
    *(uint4*)(bs[c] + off0 + 256) = *(const uint4*)&vb[8];
  }
}

// max3 tree over the 16 acc regs (targets) + running max: 8 VALU ops.
__device__ __forceinline__ float tree17(const f32x16& c, float m) {
  float t0 = fmaxf(fmaxf(c[0],  c[1]),  c[2]);    // v_max3_f32
  float t1 = fmaxf(fmaxf(c[3],  c[4]),  c[5]);
  float t2 = fmaxf(fmaxf(c[6],  c[7]),  c[8]);
  float t3 = fmaxf(fmaxf(c[9],  c[10]), c[11]);
  float t4 = fmaxf(fmaxf(c[12], c[13]), c[14]);
  float u0 = fmaxf(fmaxf(t0, t1), t2);
  float u1 = fmaxf(fmaxf(t3, t4), c[15]);
  return fmaxf(fmaxf(u0, u1), m);
}

// grid = 2(dir) x 4(b) x 16(ig: 512 queries) x 8(jc) = 1024 blocks x 4 waves.
// Wave owns 4 query-tiles (128 queries); block stages 1024 targets (32 KB,
// +1 tile pad for prefetch) and loops 32 target tiles.
__global__ __launch_bounds__(256, 4) void chamfer_mfma(
    const unsigned short* __restrict__ a1, const unsigned short* __restrict__ a2,
    const unsigned short* __restrict__ b1, const unsigned short* __restrict__ b2,
    unsigned* __restrict__ rowbuf) {
  __shared__ __align__(16) unsigned short sB[(JCHUNK + 32) * 16];  // 33 KB

  int bid = blockIdx.x;
  int jc  = bid & (NJ - 1);
  int ig  = (bid >> 3) & 15;
  int b   = (bid >> 7) & 3;
  int dir = bid >> 9;

  const unsigned short* A = dir ? a2 : a1;   // queries (tiled rep)
  const unsigned short* B = dir ? b1 : b2;   // targets (tiled rep)

  int wave = threadIdx.x >> 6;
  int lane = threadIdx.x & 63;
  int p = lane & 31, h = lane >> 5;

  // ---- stage 32 KB target chunk linearly: 4 waves x 8 x (64 x 16 B) ----
  {
    const char* gb = (const char*)B + (size_t)b * 262144 + (size_t)jc * 32768
                     + wave * 8192 + lane * 16;
    char* lb = (char*)sB + wave * 8192;
    #pragma unroll
    for (int k = 0; k < 8; ++k) {
      __builtin_amdgcn_global_load_lds(
          (const __attribute__((address_space(1))) unsigned int*)(gb + k * 1024),
          (__attribute__((address_space(3))) unsigned int*)(lb + k * 1024),
          16, 0, 0);
    }
  }

  // query fragments: 4 consecutive tiles, contiguous 16 B/lane
  int q0 = ig * 512 + wave * 128;
  const unsigned short* Ap =
      A + (size_t)b * 131072 + (size_t)(q0 >> 5) * 512 + h * 256 + p * 8;
  short8v aq0 = *(const short8v*)(const void*)(Ap);
  short8v aq1 = *(const short8v*)(const void*)(Ap + 512);
  short8v aq2 = *(const short8v*)(const void*)(Ap + 1024);
  short8v aq3 = *(const short8v*)(const void*)(Ap + 1536);

  f32x16 zero;
  #pragma unroll
  for (int i = 0; i < 16; ++i) zero[i] = 0.0f;
  float m0 = -3.4e38f, m1 = -3.4e38f, m2 = -3.4e38f, m3 = -3.4e38f;

  __syncthreads();   // drains global_load_lds + barrier (only barrier)

  const char* sp = (const char*)sB + lane * 16;   // sequential: conflict-free
  short8v bt = *(const short8v*)(const void*)(sp);

  #pragma unroll 1
  for (int jt = 0; jt < JTILES; ++jt) {
    short8v btn = *(const short8v*)(const void*)(sp + (size_t)(jt + 1) * 1024);
    // swapped operands: rows(regs)=targets, cols(lanes)=queries
    f32x16 c0 = __builtin_amdgcn_mfma_f32_32x32x16_bf16(bt, aq0, zero, 0, 0, 0);
    f32x16 c1 = __builtin_amdgcn_mfma_f32_32x32x16_bf16(bt, aq1, zero, 0, 0, 0);
    f32x16 c2 = __builtin_amdgcn_mfma_f32_32x32x16_bf16(bt, aq2, zero, 0, 0, 0);
    f32x16 c3 = __builtin_amdgcn_mfma_f32_32x32x16_bf16(bt, aq3, zero, 0, 0, 0);
    m0 = tree17(c0, m0);   // in-lane: 16 targets for THIS lane's query
    m1 = tree17(c1, m1);
    m2 = tree17(c2, m2);
    m3 = tree17(c3, m3);
    bt = btn;
  }

  // lane L and L^32 hold the two target-halves of the same query: 1 shfl each
  m0 = fmaxf(m0, __shfl_xor(m0, 32, 64));
  m1 = fmaxf(m1, __shfl_xor(m1, 32, 64));
  m2 = fmaxf(m2, __shfl_xor(m2, 32, 64));
  m3 = fmaxf(m3, __shfl_xor(m3, 32, 64));

  unsigned* rb = rowbuf + ((size_t)dir * BATCH + b) * NPTS + q0;
  if (lane < 32) {                       // NJ=8 contenders, deterministic
    atomicMax(rb + p,       enc_f32(m0));
    atomicMax(rb + 32 + p,  enc_f32(m1));
    atomicMax(rb + 64 + p,  enc_f32(m2));
    atomicMax(rb + 96 + p,  enc_f32(m3));
  }
}

__global__ __launch_bounds__(256) void loss_part(
    const unsigned* __restrict__ rowbuf, float* __restrict__ partials) {
  int idx = blockIdx.x * 256 + threadIdx.x;   // 64 blocks
  uint4 u = ((const uint4*)rowbuf)[idx];
  float s = -2.0f * (((dec_f32(u.x) + dec_f32(u.y)) +
                      (dec_f32(u.z) + dec_f32(u.w))));
  #pragma unroll
  for (int off = 32; off > 0; off >>= 1) s += __shfl_down(s, off, 64);
  __shared__ float wsum[4];
  if ((threadIdx.x & 63) == 0) wsum[threadIdx.x >> 6] = s;
  __syncthreads();
  if (threadIdx.x == 0)
    partials[blockIdx.x] = (wsum[0] + wsum[1]) + (wsum[2] + wsum[3]);
}

__global__ __launch_bounds__(64) void loss_fin(
    const float* __restrict__ partials, float* __restrict__ out) {
  float s = partials[threadIdx.x];   // 64 partials, 1 wave
  #pragma unroll
  for (int off = 32; off > 0; off >>= 1) s += __shfl_down(s, off, 64);
  if (threadIdx.x == 0) out[0] = s;
}

extern "C" void kernel_launch(void* const* d_in, const int* in_sizes, int n_in,
                              void* d_out, int out_size, void* d_ws, size_t ws_size,
                              hipStream_t stream) {
  const float* c1 = (const float*)d_in[0];
  const float* c2 = (const float*)d_in[1];
  float* out = (float*)d_out;

  char* ws = (char*)d_ws;
  unsigned* rowbuf = (unsigned*)ws;                          // 65536 u32 = 256 KB
  float* partials = (float*)(ws + (size_t)NSLOTS * 4);       // 64 f32
  unsigned short* a1 = (unsigned short*)(ws + (size_t)NSLOTS * 4 + 1024);
  unsigned short* a2 = a1 + (size_t)BATCH * NPTS * 16;       // 1 MB each
  unsigned short* b1 = a2 + (size_t)BATCH * NPTS * 16;
  unsigned short* b2 = b1 + (size_t)BATCH * NPTS * 16;

  prep<<<(BATCH * NPTS) / 256, 256, 0, stream>>>(c1, c2, a1, a2, b1, b2, rowbuf);
  chamfer_mfma<<<2 * BATCH * 16 * NJ, 256, 0, stream>>>(a1, a2, b1, b2, rowbuf);
  loss_part<<<64, 256, 0, stream>>>(rowbuf, partials);
  loss_fin<<<1, 64, 0, stream>>>(partials, out);
}